// Round 5
// baseline (3085.938 us; speedup 1.0000x reference)
//
#include <hip/hip_runtime.h>
#include <hip/hip_bf16.h>

#define NN 200000
#define NE 3200000
#define NG 4096
#define INC 78
#define C1 64
#define C2 128
#define ODIM 128
#define KP1 96      // layer-1 K padded to 3x32

#define BSZ 256     // nodes per bucket
#define NBKT 782    // ceil(NN/BSZ)
#define NBLK 196    // scatter blocks
#define EPB 16327   // ceil(NE/NBLK)
#define SCN (NBKT*NBLK)

using bf16 = __hip_bfloat16;
typedef __attribute__((ext_vector_type(8))) short bf16x8;
typedef __attribute__((ext_vector_type(4))) float f32x4;

static inline size_t alignup(size_t x) { return (x + 255) & ~size_t(255); }

__device__ __forceinline__ float bf2f(unsigned short u) {
    return __uint_as_float(((unsigned)u) << 16);
}
__device__ __forceinline__ unsigned short f2bf(float f) {
    __hip_bfloat16 h = __float2bfloat16(f);
    return *reinterpret_cast<unsigned short*>(&h);
}

// ---------- edge binning: per-(bucket,block) histogram ----------
__global__ void hist1_kernel(const int* __restrict__ dst, int* __restrict__ histM) {
    __shared__ int lh[NBKT];
    for (int j = threadIdx.x; j < NBKT; j += 256) lh[j] = 0;
    __syncthreads();
    int e0 = blockIdx.x * EPB;
    int e1 = e0 + EPB; if (e1 > NE) e1 = NE;
    for (int e = e0 + threadIdx.x; e < e1; e += 256)
        atomicAdd(&lh[((unsigned)dst[e]) >> 8], 1);
    __syncthreads();
    for (int j = threadIdx.x; j < NBKT; j += 256)
        histM[j * NBLK + blockIdx.x] = lh[j];
}

// ---------- generic exclusive scan over SCN elements (in-place ok) ----------
__global__ void scan1_kernel(int* __restrict__ data, int* __restrict__ bsum, int n) {
    __shared__ int tmp[256];
    int tid = threadIdx.x, gid = blockIdx.x * 256 + tid;
    int v = (gid < n) ? data[gid] : 0;
    tmp[tid] = v;
    __syncthreads();
    for (int off = 1; off < 256; off <<= 1) {
        int t = (tid >= off) ? tmp[tid - off] : 0;
        __syncthreads();
        tmp[tid] += t;
        __syncthreads();
    }
    if (gid < n) data[gid] = tmp[tid] - v;
    if (tid == 255) bsum[blockIdx.x] = tmp[255];
}

__global__ void scan2_kernel(int* __restrict__ bsum, int nb) {
    __shared__ int tmp[1024];
    int tid = threadIdx.x;
    int v = (tid < nb) ? bsum[tid] : 0;
    tmp[tid] = v;
    __syncthreads();
    for (int off = 1; off < 1024; off <<= 1) {
        int t = (tid >= off) ? tmp[tid - off] : 0;
        __syncthreads();
        tmp[tid] += t;
        __syncthreads();
    }
    if (tid < nb) bsum[tid] = tmp[tid] - v;
}

__global__ void scan3_kernel(int* __restrict__ data, const int* __restrict__ bsum, int n) {
    int gid = blockIdx.x * 256 + threadIdx.x;
    if (gid < n) data[gid] += bsum[blockIdx.x];
}

__global__ void extract_kernel(const int* __restrict__ histM, int* __restrict__ boff) {
    int j = blockIdx.x * 256 + threadIdx.x;
    if (j < NBKT) boff[j] = histM[(size_t)j * NBLK];
    if (j == NBKT) boff[NBKT] = NE;
}

// ---------- scatter edges into bucket-sorted ebuf (coherent runs) ----------
__global__ void scatter2_kernel(const int* __restrict__ src, const int* __restrict__ dst,
                                const int* __restrict__ histM, unsigned* __restrict__ ebuf) {
    __shared__ int lc[NBKT];
    for (int j = threadIdx.x; j < NBKT; j += 256) lc[j] = histM[j * NBLK + blockIdx.x];
    __syncthreads();
    int e0 = blockIdx.x * EPB;
    int e1 = e0 + EPB; if (e1 > NE) e1 = NE;
    for (int e = e0 + threadIdx.x; e < e1; e += 256) {
        int d = dst[e];
        int s = src[e];
        int pos = atomicAdd(&lc[((unsigned)d) >> 8], 1);
        ebuf[pos] = ((unsigned)s << 8) | (unsigned)(d & 255);
    }
}

// ---------- per-node degree + dinv from sorted records ----------
__global__ void deg2_kernel(const unsigned* __restrict__ ebuf, const int* __restrict__ boff,
                            float* __restrict__ dinv) {
    __shared__ int cnt[BSZ];
    cnt[threadIdx.x] = 0;
    __syncthreads();
    int b = blockIdx.x;
    int s0 = boff[b], s1 = boff[b + 1];
    for (int i = s0 + threadIdx.x; i < s1; i += 256)
        atomicAdd(&cnt[ebuf[i] & 255], 1);
    __syncthreads();
    int node = b * BSZ + threadIdx.x;
    if (node < NN) dinv[node] = rsqrtf((float)cnt[threadIdx.x] + 1.0f);
}

// ---------- per-graph node counts ----------
__global__ void count_kernel(const int* __restrict__ batch, float* __restrict__ cnt) {
    int n = blockIdx.x * 256 + threadIdx.x;
    if (n < NN) atomicAdd(&cnt[batch[n]], 1.0f);
}

// ---------- weight conversion: Wt[c][k] = bf16(W[k][c]), k zero-padded to KP ----------
__global__ void convw_kernel(const float* __restrict__ W, unsigned short* __restrict__ Wt,
                             int N, int K, int KP) {
    int idx = blockIdx.x * 256 + threadIdx.x;
    if (idx >= N * KP) return;
    int c = idx / KP, k = idx % KP;
    float f = (k < K) ? W[k * N + c] : 0.f;
    Wt[idx] = f2bf(f);
}

// ---------- gemm1: hw1 = bf16(x @ W1), reads x f32 directly ----------
__global__ __launch_bounds__(256) void gemm1_mfma(const float* __restrict__ x,
                                                  const unsigned short* __restrict__ Wt1,
                                                  unsigned short* __restrict__ hw1) {
    int wave = threadIdx.x >> 6, lane = threadIdx.x & 63;
    int r = lane & 15, kg = lane >> 4;
    int row0 = blockIdx.x * 64 + wave * 16;
    const float* arow = x + (size_t)(row0 + r) * INC;
    bf16x8 a[3];
    #pragma unroll
    for (int t = 0; t < 3; ++t) {
        union { bf16x8 v; unsigned short u[8]; } tmp;
        #pragma unroll
        for (int j = 0; j < 8; ++j) {
            int k = t * 32 + kg * 8 + j;
            tmp.u[j] = (k < INC) ? f2bf(arow[k]) : (unsigned short)0;
        }
        a[t] = tmp.v;
    }
    #pragma unroll
    for (int nt = 0; nt < 4; ++nt) {
        const unsigned short* wrow = Wt1 + (size_t)(nt * 16 + r) * KP1 + kg * 8;
        bf16x8 b0 = *(const bf16x8*)(wrow);
        bf16x8 b1 = *(const bf16x8*)(wrow + 32);
        bf16x8 b2 = *(const bf16x8*)(wrow + 64);
        f32x4 acc = {0.f, 0.f, 0.f, 0.f};
        acc = __builtin_amdgcn_mfma_f32_16x16x32_bf16(a[0], b0, acc, 0, 0, 0);
        acc = __builtin_amdgcn_mfma_f32_16x16x32_bf16(a[1], b1, acc, 0, 0, 0);
        acc = __builtin_amdgcn_mfma_f32_16x16x32_bf16(a[2], b2, acc, 0, 0, 0);
        unsigned short* cb = hw1 + (size_t)(row0 + kg * 4) * C1 + nt * 16 + r;
        #pragma unroll
        for (int i = 0; i < 4; ++i) cb[(size_t)i * C1] = f2bf(acc[i]);
    }
}

// ---------- LDS-accumulated aggregation over one bucket (no global atomics) ----------
// EP=1: out = bf16(relu(dinv*(acc + self*dinv) + bias))   (layer-1 h1)
// EP=2: out = bf16(dinv*(acc + self*dinv))                (layer-2 pre-GEMM aggregate)
template <int EP>
__global__ __launch_bounds__(256) void agg_lds_kernel(
    const unsigned* __restrict__ ebuf, const int* __restrict__ boff,
    const float* __restrict__ dinv, const unsigned short* __restrict__ vin,
    const float* __restrict__ bias, unsigned short* __restrict__ vout) {
    __shared__ float acc[BSZ * 64];
    for (int i = threadIdx.x; i < BSZ * 64; i += 256) acc[i] = 0.f;
    __syncthreads();
    int b = blockIdx.x;
    int s0 = boff[b], s1 = boff[b + 1];
    int lane = threadIdx.x & 63, wave = threadIdx.x >> 6;
    const int U = 4;
    for (int e0 = s0 + wave * U; e0 < s1; e0 += 4 * U) {
        int m = s1 - e0; if (m > U) m = U;
        float v[U], w[U];
        int dl[U];
        #pragma unroll
        for (int k = 0; k < U; ++k) {
            if (k < m) {
                unsigned rec = ebuf[e0 + k];
                int s = rec >> 8;
                dl[k] = rec & 255;
                w[k] = dinv[s];
                v[k] = bf2f(vin[(size_t)s * 64 + lane]);
            } else { dl[k] = 0; w[k] = 0.f; v[k] = 0.f; }
        }
        #pragma unroll
        for (int k = 0; k < U; ++k) {
            if (k < m) atomicAdd(&acc[dl[k] * 64 + lane], v[k] * w[k]);
        }
    }
    __syncthreads();
    for (int i = threadIdx.x; i < BSZ * 64; i += 256) {
        int nl = i >> 6, c = i & 63;
        int node = b * BSZ + nl;
        if (node < NN) {
            float d = dinv[node];
            float sv = bf2f(vin[(size_t)node * 64 + c]);
            float val = d * (acc[i] + sv * d);
            if (EP == 1) val = fmaxf(val + bias[c], 0.f);
            vout[(size_t)node * 64 + c] = f2bf(val);
        }
    }
}

// ---------- gemm2 + bias + relu + pooled (LDS graph slots) ----------
__global__ __launch_bounds__(256) void gemm2p_mfma(const unsigned short* __restrict__ aggH,
                                                   const unsigned short* __restrict__ Wt2,
                                                   const float* __restrict__ b2,
                                                   const int* __restrict__ batch,
                                                   float* __restrict__ pooled) {
    __shared__ float ps[8 * 128];
    for (int i = threadIdx.x; i < 8 * 128; i += 256) ps[i] = 0.f;
    int wave = threadIdx.x >> 6, lane = threadIdx.x & 63;
    int r = lane & 15, kg = lane >> 4;
    int row0 = blockIdx.x * 64 + wave * 16;
    int gmin = batch[blockIdx.x * 64];
    __syncthreads();
    const unsigned short* arow = aggH + (size_t)(row0 + r) * 64 + kg * 8;
    bf16x8 a0 = *(const bf16x8*)(arow);
    bf16x8 a1 = *(const bf16x8*)(arow + 32);
    #pragma unroll
    for (int nt = 0; nt < 8; ++nt) {
        const unsigned short* wrow = Wt2 + (size_t)(nt * 16 + r) * C1 + kg * 8;
        bf16x8 b0 = *(const bf16x8*)(wrow);
        bf16x8 b1 = *(const bf16x8*)(wrow + 32);
        f32x4 acc = {0.f, 0.f, 0.f, 0.f};
        acc = __builtin_amdgcn_mfma_f32_16x16x32_bf16(a0, b0, acc, 0, 0, 0);
        acc = __builtin_amdgcn_mfma_f32_16x16x32_bf16(a1, b1, acc, 0, 0, 0);
        int col = nt * 16 + r;
        float bb = b2[col];
        #pragma unroll
        for (int i = 0; i < 4; ++i) {
            int row = row0 + kg * 4 + i;
            float v = fmaxf(acc[i] + bb, 0.f);
            int g = batch[row];
            int off = g - gmin;
            if (off < 8) atomicAdd(&ps[off * 128 + col], v);
            else atomicAdd(&pooled[(size_t)g * 128 + col], v);
        }
    }
    __syncthreads();
    for (int i = threadIdx.x; i < 8 * 128; i += 256) {
        float v = ps[i];
        if (v != 0.f) atomicAdd(&pooled[(size_t)(gmin + (i >> 7)) * 128 + (i & 127)], v);
    }
}

// ---------- final FC ----------
__global__ void final_kernel(const float* __restrict__ pooled, const float* __restrict__ cnt,
                             const float* __restrict__ fcw, const float* __restrict__ fcb,
                             float* __restrict__ out) {
    int idx = blockIdx.x * 256 + threadIdx.x;
    if (idx < NG * ODIM) {
        int g = idx >> 7;
        int o = idx & 127;
        float inv = 1.0f / fmaxf(cnt[g], 1.0f);
        float acc = fcb[o];
        const float* pr = pooled + (size_t)g * C2;
        #pragma unroll
        for (int k = 0; k < C2; ++k) acc += pr[k] * inv * fcw[k * ODIM + o];
        out[idx] = acc;
    }
}

extern "C" void kernel_launch(void* const* d_in, const int* in_sizes, int n_in,
                              void* d_out, int out_size, void* d_ws, size_t ws_size,
                              hipStream_t stream) {
    const float* x   = (const float*)d_in[0];
    const int*   ei  = (const int*)d_in[1];
    const int*   bat = (const int*)d_in[2];
    const float* W1  = (const float*)d_in[3];
    const float* b1  = (const float*)d_in[4];
    const float* W2  = (const float*)d_in[5];
    const float* b2  = (const float*)d_in[6];
    const float* fcw = (const float*)d_in[7];
    const float* fcb = (const float*)d_in[8];
    float* out = (float*)d_out;

    const int* src = ei;        // edge_index[0]
    const int* dst = ei + NE;   // edge_index[1]

    char* ws = (char*)d_ws;
    int* histM   = (int*)ws;            ws += alignup((size_t)SCN * 4);
    int* bsum    = (int*)ws;            ws += alignup(1024 * 4);
    int* boff    = (int*)ws;            ws += alignup((size_t)(NBKT + 1) * 4);
    float* dinv  = (float*)ws;          ws += alignup((size_t)NN * 4);
    unsigned* ebuf = (unsigned*)ws;     ws += alignup((size_t)NE * 4);
    unsigned short* hw1 = (unsigned short*)ws; ws += alignup((size_t)NN * C1 * 2);
    unsigned short* aggH = hw1;         // reuse: hw1 dead after agg1
    unsigned short* h1 = (unsigned short*)ws;  ws += alignup((size_t)NN * C1 * 2);
    unsigned short* Wt1 = (unsigned short*)ws; ws += alignup((size_t)C1 * KP1 * 2);
    unsigned short* Wt2 = (unsigned short*)ws; ws += alignup((size_t)C2 * C1 * 2);
    float* pooled = (float*)ws;         ws += alignup((size_t)NG * C2 * 4);
    float* cnt    = (float*)ws;         ws += alignup((size_t)NG * 4);

    hipMemsetAsync(pooled, 0, (size_t)NG * C2 * 4, stream);
    hipMemsetAsync(cnt, 0, (size_t)NG * 4, stream);

    // ---- edge binning (bucket = dst>>8) ----
    hist1_kernel<<<NBLK, 256, 0, stream>>>(dst, histM);
    const int SCB = (SCN + 255) / 256;  // 599
    scan1_kernel<<<SCB, 256, 0, stream>>>(histM, bsum, SCN);
    scan2_kernel<<<1, 1024, 0, stream>>>(bsum, SCB);
    scan3_kernel<<<SCB, 256, 0, stream>>>(histM, bsum, SCN);
    extract_kernel<<<4, 256, 0, stream>>>(histM, boff);
    scatter2_kernel<<<NBLK, 256, 0, stream>>>(src, dst, histM, ebuf);
    deg2_kernel<<<NBKT, 256, 0, stream>>>(ebuf, boff, dinv);
    count_kernel<<<(NN + 255) / 256, 256, 0, stream>>>(bat, cnt);

    // ---- weights ----
    convw_kernel<<<(C1 * KP1 + 255) / 256, 256, 0, stream>>>(W1, Wt1, C1, INC, KP1);
    convw_kernel<<<(C2 * C1 + 255) / 256, 256, 0, stream>>>(W2, Wt2, C2, C1, C1);

    // ---- layer 1: GEMM then aggregate ----
    gemm1_mfma<<<NN / 64, 256, 0, stream>>>(x, Wt1, hw1);
    agg_lds_kernel<1><<<NBKT, 256, 0, stream>>>(ebuf, boff, dinv, hw1, b1, h1);

    // ---- layer 2: aggregate first (linearity), then GEMM + relu + pool ----
    agg_lds_kernel<2><<<NBKT, 256, 0, stream>>>(ebuf, boff, dinv, h1, b1, aggH);
    gemm2p_mfma<<<NN / 64, 256, 0, stream>>>(aggH, Wt2, b2, bat, pooled);

    // ---- final FC ----
    final_kernel<<<(NG * ODIM + 255) / 256, 256, 0, stream>>>(pooled, cnt, fcw, fcb, out);
}

// Round 6
// 576.916 us; speedup vs baseline: 5.3490x; 5.3490x over previous
//
#include <hip/hip_runtime.h>
#include <hip/hip_bf16.h>

#define NN 200000
#define NE 3200000
#define NG 4096
#define INC 78
#define C1 64
#define C2 128
#define ODIM 128
#define KP1 96      // layer-1 K padded to 3x32

#define BSZ 256     // nodes per bucket
#define NBKT 782    // ceil(NN/BSZ)
#define NBLK 196    // binning blocks
#define EPB 16327   // ceil(NE/NBLK)
#define SCN (NBKT*NBLK)

using bf16 = __hip_bfloat16;
typedef __attribute__((ext_vector_type(8))) short bf16x8;
typedef __attribute__((ext_vector_type(4))) float f32x4;

static inline size_t alignup(size_t x) { return (x + 255) & ~size_t(255); }

__device__ __forceinline__ float bf2f(unsigned short u) {
    return __uint_as_float(((unsigned)u) << 16);
}
__device__ __forceinline__ unsigned short f2bf(float f) {
    __hip_bfloat16 h = __float2bfloat16(f);
    return *reinterpret_cast<unsigned short*>(&h);
}

// ---------- phase 1: per-(bucket,block) histogram of dst>>8 ----------
__global__ void hist1_kernel(const int* __restrict__ dst, int* __restrict__ histM) {
    __shared__ int lh[NBKT];
    for (int j = threadIdx.x; j < NBKT; j += 256) lh[j] = 0;
    __syncthreads();
    int e0 = blockIdx.x * EPB;
    int e1 = e0 + EPB; if (e1 > NE) e1 = NE;
    for (int e = e0 + threadIdx.x; e < e1; e += 256)
        atomicAdd(&lh[((unsigned)dst[e]) >> 8], 1);
    __syncthreads();
    for (int j = threadIdx.x; j < NBKT; j += 256)
        histM[j * NBLK + blockIdx.x] = lh[j];
}

// ---------- generic exclusive scan (separate in/out ok, in==out ok) ----------
__global__ void scan1_kernel(const int* __restrict__ in, int* __restrict__ out,
                             int* __restrict__ bsum, int n) {
    __shared__ int tmp[256];
    int tid = threadIdx.x, gid = blockIdx.x * 256 + tid;
    int v = (gid < n) ? in[gid] : 0;
    tmp[tid] = v;
    __syncthreads();
    for (int off = 1; off < 256; off <<= 1) {
        int t = (tid >= off) ? tmp[tid - off] : 0;
        __syncthreads();
        tmp[tid] += t;
        __syncthreads();
    }
    if (gid < n) out[gid] = tmp[tid] - v;
    if (tid == 255) bsum[blockIdx.x] = tmp[255];
}

__global__ void scan2_kernel(int* __restrict__ bsum, int nb) {
    __shared__ int tmp[1024];
    int tid = threadIdx.x;
    int v = (tid < nb) ? bsum[tid] : 0;
    tmp[tid] = v;
    __syncthreads();
    for (int off = 1; off < 1024; off <<= 1) {
        int t = (tid >= off) ? tmp[tid - off] : 0;
        __syncthreads();
        tmp[tid] += t;
        __syncthreads();
    }
    if (tid < nb) bsum[tid] = tmp[tid] - v;
}

__global__ void scan3_kernel(int* __restrict__ data, const int* __restrict__ bsum,
                             int n, int tailval) {
    int gid = blockIdx.x * 256 + threadIdx.x;
    if (gid < n) data[gid] += bsum[blockIdx.x];
    if (gid == 0) data[n] = tailval;
}

__global__ void extract_kernel(const int* __restrict__ histM, int* __restrict__ boff) {
    int j = blockIdx.x * 256 + threadIdx.x;
    if (j < NBKT) boff[j] = histM[(size_t)j * NBLK];
    if (j == NBKT) boff[NBKT] = NE;
}

// ---------- phase 2: scatter edges into bucket-sorted ebuf (coherent runs) ----------
// record = (src << 8) | (dst & 255);  src < 2^24 fits.
__global__ void scatter2_kernel(const int* __restrict__ src, const int* __restrict__ dst,
                                const int* __restrict__ histM, unsigned* __restrict__ ebuf) {
    __shared__ int lc[NBKT];
    for (int j = threadIdx.x; j < NBKT; j += 256) lc[j] = histM[j * NBLK + blockIdx.x];
    __syncthreads();
    int e0 = blockIdx.x * EPB;
    int e1 = e0 + EPB; if (e1 > NE) e1 = NE;
    for (int e = e0 + threadIdx.x; e < e1; e += 256) {
        int d = dst[e];
        int s = src[e];
        int pos = atomicAdd(&lc[((unsigned)d) >> 8], 1);
        ebuf[pos] = ((unsigned)s << 8) | (unsigned)(d & 255);
    }
}

// ---------- per-node degree (int) + dinv from bucket records ----------
__global__ void deg2_kernel(const unsigned* __restrict__ ebuf, const int* __restrict__ boff,
                            int* __restrict__ degN, float* __restrict__ dinv) {
    __shared__ int cnt[BSZ];
    cnt[threadIdx.x] = 0;
    __syncthreads();
    int b = blockIdx.x;
    int s0 = boff[b], s1 = boff[b + 1];
    for (int i = s0 + threadIdx.x; i < s1; i += 256)
        atomicAdd(&cnt[ebuf[i] & 255], 1);
    __syncthreads();
    int node = b * BSZ + threadIdx.x;
    if (node < NN) {
        degN[node] = cnt[threadIdx.x];
        dinv[node] = rsqrtf((float)cnt[threadIdx.x] + 1.0f);
    }
}

// ---------- phase 3: place records into true CSR order (writes L2-local) ----------
__global__ void csrfill_kernel(const unsigned* __restrict__ ebuf, const int* __restrict__ boff,
                               const int* __restrict__ rs, unsigned* __restrict__ csr) {
    __shared__ int lc[BSZ];
    __shared__ int rsl[BSZ];
    int b = blockIdx.x;
    int node = b * BSZ + threadIdx.x;
    lc[threadIdx.x] = 0;
    rsl[threadIdx.x] = (node < NN) ? rs[node] : 0;
    __syncthreads();
    int s0 = boff[b], s1 = boff[b + 1];
    for (int i = s0 + threadIdx.x; i < s1; i += 256) {
        unsigned rec = ebuf[i];
        int nl = rec & 255;
        int pos = atomicAdd(&lc[nl], 1);
        csr[rsl[nl] + pos] = rec >> 8;   // src only
    }
}

// ---------- per-graph node counts ----------
__global__ void count_kernel(const int* __restrict__ batch, float* __restrict__ cnt) {
    int n = blockIdx.x * 256 + threadIdx.x;
    if (n < NN) atomicAdd(&cnt[batch[n]], 1.0f);
}

// ---------- weight conversion: Wt[c][k] = bf16(W[k][c]), k zero-padded to KP ----------
__global__ void convw_kernel(const float* __restrict__ W, unsigned short* __restrict__ Wt,
                             int N, int K, int KP) {
    int idx = blockIdx.x * 256 + threadIdx.x;
    if (idx >= N * KP) return;
    int c = idx / KP, k = idx % KP;
    float f = (k < K) ? W[k * N + c] : 0.f;
    Wt[idx] = f2bf(f);
}

// ---------- gemm1: hw1s = bf16(dinv[n] * (x @ W1)) ----------
__global__ __launch_bounds__(256) void gemm1_mfma(const float* __restrict__ x,
                                                  const unsigned short* __restrict__ Wt1,
                                                  const float* __restrict__ dinv,
                                                  unsigned short* __restrict__ hw1s) {
    int wave = threadIdx.x >> 6, lane = threadIdx.x & 63;
    int r = lane & 15, kg = lane >> 4;
    int row0 = blockIdx.x * 64 + wave * 16;
    const float* arow = x + (size_t)(row0 + r) * INC;
    bf16x8 a[3];
    #pragma unroll
    for (int t = 0; t < 3; ++t) {
        union { bf16x8 v; unsigned short u[8]; } tmp;
        #pragma unroll
        for (int j = 0; j < 8; ++j) {
            int k = t * 32 + kg * 8 + j;
            tmp.u[j] = (k < INC) ? f2bf(arow[k]) : (unsigned short)0;
        }
        a[t] = tmp.v;
    }
    float dsc[4];
    #pragma unroll
    for (int i = 0; i < 4; ++i) dsc[i] = dinv[row0 + kg * 4 + i];
    #pragma unroll
    for (int nt = 0; nt < 4; ++nt) {
        const unsigned short* wrow = Wt1 + (size_t)(nt * 16 + r) * KP1 + kg * 8;
        bf16x8 b0 = *(const bf16x8*)(wrow);
        bf16x8 b1 = *(const bf16x8*)(wrow + 32);
        bf16x8 b2 = *(const bf16x8*)(wrow + 64);
        f32x4 acc = {0.f, 0.f, 0.f, 0.f};
        acc = __builtin_amdgcn_mfma_f32_16x16x32_bf16(a[0], b0, acc, 0, 0, 0);
        acc = __builtin_amdgcn_mfma_f32_16x16x32_bf16(a[1], b1, acc, 0, 0, 0);
        acc = __builtin_amdgcn_mfma_f32_16x16x32_bf16(a[2], b2, acc, 0, 0, 0);
        unsigned short* cb = hw1s + (size_t)(row0 + kg * 4) * C1 + nt * 16 + r;
        #pragma unroll
        for (int i = 0; i < 4; ++i) cb[(size_t)i * C1] = f2bf(acc[i] * dsc[i]);
    }
}

// ---------- wave-per-node CSR gather; values pre-scaled so inner loop is add-only ----------
// EP=1: out = bf16(relu(dinv*(acc+self) + bias) * dinv)   (h1 pre-scaled for next gather)
// EP=2: out = bf16(dinv*(acc+self))                        (aggH for gemm2)
template <int EP>
__global__ __launch_bounds__(256) void agg_csr_kernel(
    const unsigned* __restrict__ csr, const int* __restrict__ rs,
    const float* __restrict__ dinv, const unsigned short* __restrict__ vin,
    const float* __restrict__ bias, unsigned short* __restrict__ vout) {
    int node = blockIdx.x * 4 + (threadIdx.x >> 6);
    if (node >= NN) return;
    int c = threadIdx.x & 63;
    int start = rs[node], len = rs[node + 1] - start;
    float acc = 0.f;
    int e = 0;
    for (; e + 4 <= len; e += 4) {
        unsigned s0 = csr[start + e + 0];
        unsigned s1 = csr[start + e + 1];
        unsigned s2 = csr[start + e + 2];
        unsigned s3 = csr[start + e + 3];
        float v0 = bf2f(vin[(size_t)s0 * 64 + c]);
        float v1 = bf2f(vin[(size_t)s1 * 64 + c]);
        float v2 = bf2f(vin[(size_t)s2 * 64 + c]);
        float v3 = bf2f(vin[(size_t)s3 * 64 + c]);
        acc += (v0 + v1) + (v2 + v3);
    }
    for (; e < len; ++e) {
        unsigned s = csr[start + e];
        acc += bf2f(vin[(size_t)s * 64 + c]);
    }
    float d = dinv[node];
    float val = d * (acc + bf2f(vin[(size_t)node * 64 + c]));
    if (EP == 1) {
        val = fmaxf(val + bias[c], 0.f) * d;
    }
    vout[(size_t)node * 64 + c] = f2bf(val);
}

// ---------- gemm2 + bias + relu + pooled (LDS graph slots) ----------
__global__ __launch_bounds__(256) void gemm2p_mfma(const unsigned short* __restrict__ aggH,
                                                   const unsigned short* __restrict__ Wt2,
                                                   const float* __restrict__ b2,
                                                   const int* __restrict__ batch,
                                                   float* __restrict__ pooled) {
    __shared__ float ps[8 * 128];
    for (int i = threadIdx.x; i < 8 * 128; i += 256) ps[i] = 0.f;
    int wave = threadIdx.x >> 6, lane = threadIdx.x & 63;
    int r = lane & 15, kg = lane >> 4;
    int row0 = blockIdx.x * 64 + wave * 16;
    int gmin = batch[blockIdx.x * 64];
    __syncthreads();
    const unsigned short* arow = aggH + (size_t)(row0 + r) * 64 + kg * 8;
    bf16x8 a0 = *(const bf16x8*)(arow);
    bf16x8 a1 = *(const bf16x8*)(arow + 32);
    #pragma unroll
    for (int nt = 0; nt < 8; ++nt) {
        const unsigned short* wrow = Wt2 + (size_t)(nt * 16 + r) * C1 + kg * 8;
        bf16x8 b0 = *(const bf16x8*)(wrow);
        bf16x8 b1 = *(const bf16x8*)(wrow + 32);
        f32x4 acc = {0.f, 0.f, 0.f, 0.f};
        acc = __builtin_amdgcn_mfma_f32_16x16x32_bf16(a0, b0, acc, 0, 0, 0);
        acc = __builtin_amdgcn_mfma_f32_16x16x32_bf16(a1, b1, acc, 0, 0, 0);
        int col = nt * 16 + r;
        float bb = b2[col];
        #pragma unroll
        for (int i = 0; i < 4; ++i) {
            int row = row0 + kg * 4 + i;
            float v = fmaxf(acc[i] + bb, 0.f);
            int g = batch[row];
            int off = g - gmin;
            if (off < 8) atomicAdd(&ps[off * 128 + col], v);
            else atomicAdd(&pooled[(size_t)g * 128 + col], v);
        }
    }
    __syncthreads();
    for (int i = threadIdx.x; i < 8 * 128; i += 256) {
        float v = ps[i];
        if (v != 0.f) atomicAdd(&pooled[(size_t)(gmin + (i >> 7)) * 128 + (i & 127)], v);
    }
}

// ---------- final FC ----------
__global__ void final_kernel(const float* __restrict__ pooled, const float* __restrict__ cnt,
                             const float* __restrict__ fcw, const float* __restrict__ fcb,
                             float* __restrict__ out) {
    int idx = blockIdx.x * 256 + threadIdx.x;
    if (idx < NG * ODIM) {
        int g = idx >> 7;
        int o = idx & 127;
        float inv = 1.0f / fmaxf(cnt[g], 1.0f);
        float acc = fcb[o];
        const float* pr = pooled + (size_t)g * C2;
        #pragma unroll
        for (int k = 0; k < C2; ++k) acc += pr[k] * inv * fcw[k * ODIM + o];
        out[idx] = acc;
    }
}

extern "C" void kernel_launch(void* const* d_in, const int* in_sizes, int n_in,
                              void* d_out, int out_size, void* d_ws, size_t ws_size,
                              hipStream_t stream) {
    const float* x   = (const float*)d_in[0];
    const int*   ei  = (const int*)d_in[1];
    const int*   bat = (const int*)d_in[2];
    const float* W1  = (const float*)d_in[3];
    const float* b1  = (const float*)d_in[4];
    const float* W2  = (const float*)d_in[5];
    const float* b2  = (const float*)d_in[6];
    const float* fcw = (const float*)d_in[7];
    const float* fcb = (const float*)d_in[8];
    float* out = (float*)d_out;

    const int* src = ei;        // edge_index[0]
    const int* dst = ei + NE;   // edge_index[1]

    char* ws = (char*)d_ws;
    int* histM   = (int*)ws;            ws += alignup((size_t)SCN * 4);
    int* bsum    = (int*)ws;            ws += alignup(1024 * 4);
    int* boff    = (int*)ws;            ws += alignup((size_t)(NBKT + 1) * 4);
    int* degN    = (int*)ws;            ws += alignup((size_t)NN * 4);
    int* rs      = (int*)ws;            ws += alignup((size_t)(NN + 1) * 4);
    float* dinv  = (float*)ws;          ws += alignup((size_t)NN * 4);
    unsigned* ebuf = (unsigned*)ws;     ws += alignup((size_t)NE * 4);
    unsigned* csr  = (unsigned*)ws;     ws += alignup((size_t)NE * 4);
    unsigned short* hw1s = (unsigned short*)ws; ws += alignup((size_t)NN * C1 * 2);
    unsigned short* aggH = hw1s;        // reuse: hw1s dead after agg1
    unsigned short* h1s = (unsigned short*)ws;  ws += alignup((size_t)NN * C1 * 2);
    unsigned short* Wt1 = (unsigned short*)ws;  ws += alignup((size_t)C1 * KP1 * 2);
    unsigned short* Wt2 = (unsigned short*)ws;  ws += alignup((size_t)C2 * C1 * 2);
    float* pooled = (float*)ws;         ws += alignup((size_t)NG * C2 * 4);
    float* cnt    = (float*)ws;         ws += alignup((size_t)NG * 4);

    hipMemsetAsync(pooled, 0, (size_t)NG * C2 * 4, stream);
    hipMemsetAsync(cnt, 0, (size_t)NG * 4, stream);

    // ---- edge binning (bucket = dst>>8) ----
    hist1_kernel<<<NBLK, 256, 0, stream>>>(dst, histM);
    const int SCB = (SCN + 255) / 256;  // 599
    scan1_kernel<<<SCB, 256, 0, stream>>>(histM, histM, bsum, SCN);
    scan2_kernel<<<1, 1024, 0, stream>>>(bsum, SCB);
    scan3_kernel<<<SCB, 256, 0, stream>>>(histM, bsum, SCN, 0);
    extract_kernel<<<4, 256, 0, stream>>>(histM, boff);
    scatter2_kernel<<<NBLK, 256, 0, stream>>>(src, dst, histM, ebuf);

    // ---- degrees, dinv, row starts ----
    deg2_kernel<<<NBKT, 256, 0, stream>>>(ebuf, boff, degN, dinv);
    const int NNB = (NN + 255) / 256;   // 782
    scan1_kernel<<<NNB, 256, 0, stream>>>(degN, rs, bsum, NN);
    scan2_kernel<<<1, 1024, 0, stream>>>(bsum, NNB);
    scan3_kernel<<<NNB, 256, 0, stream>>>(rs, bsum, NN, NE);
    csrfill_kernel<<<NBKT, 256, 0, stream>>>(ebuf, boff, rs, csr);
    count_kernel<<<NNB, 256, 0, stream>>>(bat, cnt);

    // ---- weights ----
    convw_kernel<<<(C1 * KP1 + 255) / 256, 256, 0, stream>>>(W1, Wt1, C1, INC, KP1);
    convw_kernel<<<(C2 * C1 + 255) / 256, 256, 0, stream>>>(W2, Wt2, C2, C1, C1);

    // ---- layer 1: GEMM (pre-scaled rows) then gather ----
    gemm1_mfma<<<NN / 64, 256, 0, stream>>>(x, Wt1, dinv, hw1s);
    agg_csr_kernel<1><<<NN / 4, 256, 0, stream>>>(csr, rs, dinv, hw1s, b1, h1s);

    // ---- layer 2: aggregate first (linearity), then GEMM + relu + pool ----
    agg_csr_kernel<2><<<NN / 4, 256, 0, stream>>>(csr, rs, dinv, h1s, b1, aggH);
    gemm2p_mfma<<<NN / 64, 256, 0, stream>>>(aggH, Wt2, b2, bat, pooled);

    // ---- final FC ----
    final_kernel<<<(NG * ODIM + 255) / 256, 256, 0, stream>>>(pooled, cnt, fcw, fcb, out);
}

// Round 7
// 335.448 us; speedup vs baseline: 9.1994x; 1.7198x over previous
//
#include <hip/hip_runtime.h>
#include <hip/hip_bf16.h>

#define NN 200000
#define NE 3200000
#define NG 4096
#define INC 78
#define C1 64
#define C2 128
#define ODIM 128
#define KP1 96      // layer-1 K padded to 3x32

#define BSZ 256     // nodes per bucket
#define NBKT 782    // ceil(NN/BSZ)
#define NBLK 196    // binning blocks
#define EPB 16327   // ceil(NE/NBLK)
#define SCN (NBKT*NBLK)

using bf16 = __hip_bfloat16;
typedef __attribute__((ext_vector_type(8))) short bf16x8;
typedef __attribute__((ext_vector_type(4))) float f32x4;

static inline size_t alignup(size_t x) { return (x + 255) & ~size_t(255); }

__device__ __forceinline__ float bf2f(unsigned short u) {
    return __uint_as_float(((unsigned)u) << 16);
}
__device__ __forceinline__ float bflo(unsigned u) { return __uint_as_float(u << 16); }
__device__ __forceinline__ float bfhi(unsigned u) { return __uint_as_float(u & 0xffff0000u); }
__device__ __forceinline__ unsigned short f2bf(float f) {
    __hip_bfloat16 h = __float2bfloat16(f);
    return *reinterpret_cast<unsigned short*>(&h);
}

// ---------- phase 1: per-(bucket,block) histogram of dst>>8 ----------
__global__ void hist1_kernel(const int* __restrict__ dst, int* __restrict__ histM) {
    __shared__ int lh[NBKT];
    for (int j = threadIdx.x; j < NBKT; j += 256) lh[j] = 0;
    __syncthreads();
    int e0 = blockIdx.x * EPB;
    int e1 = e0 + EPB; if (e1 > NE) e1 = NE;
    for (int e = e0 + threadIdx.x; e < e1; e += 256)
        atomicAdd(&lh[((unsigned)dst[e]) >> 8], 1);
    __syncthreads();
    for (int j = threadIdx.x; j < NBKT; j += 256)
        histM[j * NBLK + blockIdx.x] = lh[j];
}

// ---------- generic exclusive scan ----------
__global__ void scan1_kernel(const int* __restrict__ in, int* __restrict__ out,
                             int* __restrict__ bsum, int n) {
    __shared__ int tmp[256];
    int tid = threadIdx.x, gid = blockIdx.x * 256 + tid;
    int v = (gid < n) ? in[gid] : 0;
    tmp[tid] = v;
    __syncthreads();
    for (int off = 1; off < 256; off <<= 1) {
        int t = (tid >= off) ? tmp[tid - off] : 0;
        __syncthreads();
        tmp[tid] += t;
        __syncthreads();
    }
    if (gid < n) out[gid] = tmp[tid] - v;
    if (tid == 255) bsum[blockIdx.x] = tmp[255];
}

__global__ void scan2_kernel(int* __restrict__ bsum, int nb) {
    __shared__ int tmp[1024];
    int tid = threadIdx.x;
    int v = (tid < nb) ? bsum[tid] : 0;
    tmp[tid] = v;
    __syncthreads();
    for (int off = 1; off < 1024; off <<= 1) {
        int t = (tid >= off) ? tmp[tid - off] : 0;
        __syncthreads();
        tmp[tid] += t;
        __syncthreads();
    }
    if (tid < nb) bsum[tid] = tmp[tid] - v;
}

__global__ void scan3_kernel(int* __restrict__ data, const int* __restrict__ bsum,
                             int n, int tailval) {
    int gid = blockIdx.x * 256 + threadIdx.x;
    if (gid < n) data[gid] += bsum[blockIdx.x];
    if (gid == 0) data[n] = tailval;
}

__global__ void extract_kernel(const int* __restrict__ histM, int* __restrict__ boff) {
    int j = blockIdx.x * 256 + threadIdx.x;
    if (j < NBKT) boff[j] = histM[(size_t)j * NBLK];
    if (j == NBKT) boff[NBKT] = NE;
}

// ---------- phase 2: scatter edges into bucket-sorted ebuf ----------
__global__ void scatter2_kernel(const int* __restrict__ src, const int* __restrict__ dst,
                                const int* __restrict__ histM, unsigned* __restrict__ ebuf) {
    __shared__ int lc[NBKT];
    for (int j = threadIdx.x; j < NBKT; j += 256) lc[j] = histM[j * NBLK + blockIdx.x];
    __syncthreads();
    int e0 = blockIdx.x * EPB;
    int e1 = e0 + EPB; if (e1 > NE) e1 = NE;
    for (int e = e0 + threadIdx.x; e < e1; e += 256) {
        int d = dst[e];
        int s = src[e];
        int pos = atomicAdd(&lc[((unsigned)d) >> 8], 1);
        ebuf[pos] = ((unsigned)s << 8) | (unsigned)(d & 255);
    }
}

// ---------- per-node degree + dinv from bucket records ----------
__global__ void deg2_kernel(const unsigned* __restrict__ ebuf, const int* __restrict__ boff,
                            int* __restrict__ degN, float* __restrict__ dinv) {
    __shared__ int cnt[BSZ];
    cnt[threadIdx.x] = 0;
    __syncthreads();
    int b = blockIdx.x;
    int s0 = boff[b], s1 = boff[b + 1];
    for (int i = s0 + threadIdx.x; i < s1; i += 256)
        atomicAdd(&cnt[ebuf[i] & 255], 1);
    __syncthreads();
    int node = b * BSZ + threadIdx.x;
    if (node < NN) {
        degN[node] = cnt[threadIdx.x];
        dinv[node] = rsqrtf((float)cnt[threadIdx.x] + 1.0f);
    }
}

// ---------- phase 3: place records into true CSR order ----------
__global__ void csrfill_kernel(const unsigned* __restrict__ ebuf, const int* __restrict__ boff,
                               const int* __restrict__ rs, unsigned* __restrict__ csr) {
    __shared__ int lc[BSZ];
    __shared__ int rsl[BSZ];
    int b = blockIdx.x;
    int node = b * BSZ + threadIdx.x;
    lc[threadIdx.x] = 0;
    rsl[threadIdx.x] = (node < NN) ? rs[node] : 0;
    __syncthreads();
    int s0 = boff[b], s1 = boff[b + 1];
    for (int i = s0 + threadIdx.x; i < s1; i += 256) {
        unsigned rec = ebuf[i];
        int nl = rec & 255;
        int pos = atomicAdd(&lc[nl], 1);
        csr[rsl[nl] + pos] = rec >> 8;
    }
}

// ---------- weight conversion ----------
__global__ void convw_kernel(const float* __restrict__ W, unsigned short* __restrict__ Wt,
                             int N, int K, int KP) {
    int idx = blockIdx.x * 256 + threadIdx.x;
    if (idx >= N * KP) return;
    int c = idx / KP, k = idx % KP;
    float f = (k < K) ? W[k * N + c] : 0.f;
    Wt[idx] = f2bf(f);
}

// ---------- gemm1: hw1s = bf16(dinv[n] * (x @ W1)) ----------
__global__ __launch_bounds__(256) void gemm1_mfma(const float* __restrict__ x,
                                                  const unsigned short* __restrict__ Wt1,
                                                  const float* __restrict__ dinv,
                                                  unsigned short* __restrict__ hw1s) {
    int wave = threadIdx.x >> 6, lane = threadIdx.x & 63;
    int r = lane & 15, kg = lane >> 4;
    int row0 = blockIdx.x * 64 + wave * 16;
    const float* arow = x + (size_t)(row0 + r) * INC;
    bf16x8 a[3];
    #pragma unroll
    for (int t = 0; t < 3; ++t) {
        union { bf16x8 v; unsigned short u[8]; } tmp;
        #pragma unroll
        for (int j = 0; j < 8; ++j) {
            int k = t * 32 + kg * 8 + j;
            tmp.u[j] = (k < INC) ? f2bf(arow[k]) : (unsigned short)0;
        }
        a[t] = tmp.v;
    }
    float dsc[4];
    #pragma unroll
    for (int i = 0; i < 4; ++i) dsc[i] = dinv[row0 + kg * 4 + i];
    #pragma unroll
    for (int nt = 0; nt < 4; ++nt) {
        const unsigned short* wrow = Wt1 + (size_t)(nt * 16 + r) * KP1 + kg * 8;
        bf16x8 b0 = *(const bf16x8*)(wrow);
        bf16x8 b1 = *(const bf16x8*)(wrow + 32);
        bf16x8 b2 = *(const bf16x8*)(wrow + 64);
        f32x4 acc = {0.f, 0.f, 0.f, 0.f};
        acc = __builtin_amdgcn_mfma_f32_16x16x32_bf16(a[0], b0, acc, 0, 0, 0);
        acc = __builtin_amdgcn_mfma_f32_16x16x32_bf16(a[1], b1, acc, 0, 0, 0);
        acc = __builtin_amdgcn_mfma_f32_16x16x32_bf16(a[2], b2, acc, 0, 0, 0);
        unsigned short* cb = hw1s + (size_t)(row0 + kg * 4) * C1 + nt * 16 + r;
        #pragma unroll
        for (int i = 0; i < 4; ++i) cb[(size_t)i * C1] = f2bf(acc[i] * dsc[i]);
    }
}

// ---------- quarter-wave-per-node CSR gather, 8B loads (4 ch per lane) ----------
// EP=1: out = bf16(relu(dinv*(acc+self) + bias) * dinv)
// EP=2: out = bf16(dinv*(acc+self))
template <int EP>
__global__ __launch_bounds__(256) void agg_csr_kernel(
    const unsigned* __restrict__ csr, const int* __restrict__ rs,
    const float* __restrict__ dinv, const unsigned short* __restrict__ vin,
    const float* __restrict__ bias, unsigned short* __restrict__ vout) {
    int node = blockIdx.x * 16 + (threadIdx.x >> 4);
    int l = threadIdx.x & 15;
    int c0 = l * 4;
    int start = rs[node], len = rs[node + 1] - start;
    float a0 = 0.f, a1 = 0.f, a2 = 0.f, a3 = 0.f;
    int e = 0;
    for (; e + 2 <= len; e += 2) {
        unsigned sA = csr[start + e], sB = csr[start + e + 1];
        uint2 ra = *(const uint2*)(vin + (size_t)sA * 64 + c0);
        uint2 rb = *(const uint2*)(vin + (size_t)sB * 64 + c0);
        a0 += bflo(ra.x) + bflo(rb.x);
        a1 += bfhi(ra.x) + bfhi(rb.x);
        a2 += bflo(ra.y) + bflo(rb.y);
        a3 += bfhi(ra.y) + bfhi(rb.y);
    }
    if (e < len) {
        unsigned sA = csr[start + e];
        uint2 ra = *(const uint2*)(vin + (size_t)sA * 64 + c0);
        a0 += bflo(ra.x); a1 += bfhi(ra.x); a2 += bflo(ra.y); a3 += bfhi(ra.y);
    }
    uint2 sv = *(const uint2*)(vin + (size_t)node * 64 + c0);
    a0 += bflo(sv.x); a1 += bfhi(sv.x); a2 += bflo(sv.y); a3 += bfhi(sv.y);
    float d = dinv[node];
    a0 *= d; a1 *= d; a2 *= d; a3 *= d;
    if (EP == 1) {
        a0 = fmaxf(a0 + bias[c0 + 0], 0.f) * d;
        a1 = fmaxf(a1 + bias[c0 + 1], 0.f) * d;
        a2 = fmaxf(a2 + bias[c0 + 2], 0.f) * d;
        a3 = fmaxf(a3 + bias[c0 + 3], 0.f) * d;
    }
    uint2 o;
    o.x = (unsigned)f2bf(a0) | ((unsigned)f2bf(a1) << 16);
    o.y = (unsigned)f2bf(a2) | ((unsigned)f2bf(a3) << 16);
    *(uint2*)(vout + (size_t)node * 64 + c0) = o;
}

// ---------- gemm2: h2 = bf16(relu(aggH @ W2 + b2)), streaming, no atomics ----------
__global__ __launch_bounds__(256) void gemm2_mfma(const unsigned short* __restrict__ aggH,
                                                  const unsigned short* __restrict__ Wt2,
                                                  const float* __restrict__ b2,
                                                  unsigned short* __restrict__ h2) {
    int wave = threadIdx.x >> 6, lane = threadIdx.x & 63;
    int r = lane & 15, kg = lane >> 4;
    int row0 = blockIdx.x * 64 + wave * 16;
    const unsigned short* arow = aggH + (size_t)(row0 + r) * 64 + kg * 8;
    bf16x8 a0 = *(const bf16x8*)(arow);
    bf16x8 a1 = *(const bf16x8*)(arow + 32);
    #pragma unroll
    for (int nt = 0; nt < 8; ++nt) {
        const unsigned short* wrow = Wt2 + (size_t)(nt * 16 + r) * C1 + kg * 8;
        bf16x8 b0 = *(const bf16x8*)(wrow);
        bf16x8 b1 = *(const bf16x8*)(wrow + 32);
        f32x4 acc = {0.f, 0.f, 0.f, 0.f};
        acc = __builtin_amdgcn_mfma_f32_16x16x32_bf16(a0, b0, acc, 0, 0, 0);
        acc = __builtin_amdgcn_mfma_f32_16x16x32_bf16(a1, b1, acc, 0, 0, 0);
        int col = nt * 16 + r;
        float bb = b2[col];
        unsigned short* cb = h2 + (size_t)(row0 + kg * 4) * C2 + col;
        #pragma unroll
        for (int i = 0; i < 4; ++i) cb[(size_t)i * C2] = f2bf(fmaxf(acc[i] + bb, 0.f));
    }
}

// ---------- fused mean-pool + final FC: one block per graph ----------
__device__ __forceinline__ int lbound(const int* __restrict__ a, int n, int key) {
    int lo = 0, hi = n;
    while (lo < hi) {
        int mid = (lo + hi) >> 1;
        if (a[mid] < key) lo = mid + 1; else hi = mid;
    }
    return lo;
}

__global__ __launch_bounds__(256) void pool_fc_kernel(const unsigned short* __restrict__ h2,
                                                      const int* __restrict__ batch,
                                                      const float* __restrict__ fcw,
                                                      const float* __restrict__ fcb,
                                                      float* __restrict__ out) {
    __shared__ float ps[512];
    __shared__ float pr[128];
    int g = blockIdx.x;
    int lo = lbound(batch, NN, g);
    int hi = lbound(batch, NN, g + 1);
    int cnt = hi - lo;
    int rg = threadIdx.x >> 6;      // row group 0..3
    int p = threadIdx.x & 63;       // channel pair 0..63
    float s0 = 0.f, s1 = 0.f;
    for (int r = lo + rg; r < hi; r += 4) {
        unsigned v = *(const unsigned*)(h2 + (size_t)r * C2 + p * 2);
        s0 += bflo(v);
        s1 += bfhi(v);
    }
    ps[threadIdx.x * 2 + 0] = s0;
    ps[threadIdx.x * 2 + 1] = s1;
    __syncthreads();
    if (threadIdx.x < 64) {
        float inv = 1.0f / (float)((cnt > 0) ? cnt : 1);
        int t = threadIdx.x;
        float r0 = 0.f, r1 = 0.f;
        #pragma unroll
        for (int k = 0; k < 4; ++k) {
            r0 += ps[(k * 64 + t) * 2 + 0];
            r1 += ps[(k * 64 + t) * 2 + 1];
        }
        pr[2 * t + 0] = r0 * inv;
        pr[2 * t + 1] = r1 * inv;
    }
    __syncthreads();
    if (threadIdx.x < 128) {
        int o = threadIdx.x;
        float acc = fcb[o];
        #pragma unroll 8
        for (int k = 0; k < C2; ++k) acc += pr[k] * fcw[k * ODIM + o];
        out[(size_t)g * ODIM + o] = acc;
    }
}

extern "C" void kernel_launch(void* const* d_in, const int* in_sizes, int n_in,
                              void* d_out, int out_size, void* d_ws, size_t ws_size,
                              hipStream_t stream) {
    const float* x   = (const float*)d_in[0];
    const int*   ei  = (const int*)d_in[1];
    const int*   bat = (const int*)d_in[2];
    const float* W1  = (const float*)d_in[3];
    const float* b1  = (const float*)d_in[4];
    const float* W2  = (const float*)d_in[5];
    const float* b2  = (const float*)d_in[6];
    const float* fcw = (const float*)d_in[7];
    const float* fcb = (const float*)d_in[8];
    float* out = (float*)d_out;

    const int* src = ei;        // edge_index[0]
    const int* dst = ei + NE;   // edge_index[1]

    char* ws = (char*)d_ws;
    int* histM   = (int*)ws;            ws += alignup((size_t)SCN * 4);
    int* bsum    = (int*)ws;            ws += alignup(1024 * 4);
    int* boff    = (int*)ws;            ws += alignup((size_t)(NBKT + 1) * 4);
    int* degN    = (int*)ws;            ws += alignup((size_t)NN * 4);
    int* rs      = (int*)ws;            ws += alignup((size_t)(NN + 1) * 4);
    float* dinv  = (float*)ws;          ws += alignup((size_t)NN * 4);
    unsigned short* Wt1 = (unsigned short*)ws;  ws += alignup((size_t)C1 * KP1 * 2);
    unsigned short* Wt2 = (unsigned short*)ws;  ws += alignup((size_t)C2 * C1 * 2);
    unsigned short* hw1s = (unsigned short*)ws; ws += alignup((size_t)NN * C1 * 2);
    unsigned short* aggH = hw1s;        // reuse: hw1s dead after agg_csr<1>
    // h2 (NN*128 bf16 = 51.2MB) aliases [ebuf | csr | h1s] -- all dead before gemm2
    unsigned* ebuf = (unsigned*)ws;     ws += alignup((size_t)NE * 4);
    unsigned* csr  = (unsigned*)ws;     ws += alignup((size_t)NE * 4);
    unsigned short* h1s = (unsigned short*)ws;  ws += alignup((size_t)NN * C1 * 2);
    unsigned short* h2 = (unsigned short*)ebuf;

    // ---- edge binning (bucket = dst>>8) ----
    hist1_kernel<<<NBLK, 256, 0, stream>>>(dst, histM);
    const int SCB = (SCN + 255) / 256;  // 599
    scan1_kernel<<<SCB, 256, 0, stream>>>(histM, histM, bsum, SCN);
    scan2_kernel<<<1, 1024, 0, stream>>>(bsum, SCB);
    scan3_kernel<<<SCB, 256, 0, stream>>>(histM, bsum, SCN, 0);
    extract_kernel<<<4, 256, 0, stream>>>(histM, boff);
    scatter2_kernel<<<NBLK, 256, 0, stream>>>(src, dst, histM, ebuf);

    // ---- degrees, dinv, row starts, CSR ----
    deg2_kernel<<<NBKT, 256, 0, stream>>>(ebuf, boff, degN, dinv);
    const int NNB = (NN + 255) / 256;   // 782
    scan1_kernel<<<NNB, 256, 0, stream>>>(degN, rs, bsum, NN);
    scan2_kernel<<<1, 1024, 0, stream>>>(bsum, NNB);
    scan3_kernel<<<NNB, 256, 0, stream>>>(rs, bsum, NN, NE);
    csrfill_kernel<<<NBKT, 256, 0, stream>>>(ebuf, boff, rs, csr);

    // ---- weights ----
    convw_kernel<<<(C1 * KP1 + 255) / 256, 256, 0, stream>>>(W1, Wt1, C1, INC, KP1);
    convw_kernel<<<(C2 * C1 + 255) / 256, 256, 0, stream>>>(W2, Wt2, C2, C1, C1);

    // ---- layer 1: GEMM (pre-scaled rows) then gather ----
    gemm1_mfma<<<NN / 64, 256, 0, stream>>>(x, Wt1, dinv, hw1s);
    agg_csr_kernel<1><<<NN / 16, 256, 0, stream>>>(csr, rs, dinv, hw1s, b1, h1s);

    // ---- layer 2: aggregate first (linearity), then GEMM + relu -> h2 ----
    agg_csr_kernel<2><<<NN / 16, 256, 0, stream>>>(csr, rs, dinv, h1s, b1, aggH);
    gemm2_mfma<<<NN / 64, 256, 0, stream>>>(aggH, Wt2, b2, h2);

    // ---- fused mean-pool + FC ----
    pool_fc_kernel<<<NG, 256, 0, stream>>>(h2, bat, fcw, fcb, out);
}

// Round 8
// 304.439 us; speedup vs baseline: 10.1365x; 1.1019x over previous
//
#include <hip/hip_runtime.h>
#include <hip/hip_bf16.h>

#define NN 200000
#define NE 3200000
#define NG 4096
#define INC 78
#define C1 64
#define C2 128
#define ODIM 128
#define KP1 96      // layer-1 K padded to 3x32

#define BSZ 256     // nodes per bucket
#define NBKT 782    // ceil(NN/BSZ)
#define NBLK 196    // binning blocks
#define EPB 16327   // ceil(NE/NBLK)
#define SCN (NBKT*NBLK)

using bf16 = __hip_bfloat16;
typedef __attribute__((ext_vector_type(8))) short bf16x8;
typedef __attribute__((ext_vector_type(4))) float f32x4;

static inline size_t alignup(size_t x) { return (x + 255) & ~size_t(255); }

__device__ __forceinline__ float bflo(unsigned u) { return __uint_as_float(u << 16); }
__device__ __forceinline__ float bfhi(unsigned u) { return __uint_as_float(u & 0xffff0000u); }
__device__ __forceinline__ unsigned short f2bf(float f) {
    __hip_bfloat16 h = __float2bfloat16(f);
    return *reinterpret_cast<unsigned short*>(&h);
}

// ---------- phase 1: per-(bucket,block) histogram of dst>>8 ----------
__global__ void hist1_kernel(const int* __restrict__ dst, int* __restrict__ histM) {
    __shared__ int lh[NBKT];
    for (int j = threadIdx.x; j < NBKT; j += 256) lh[j] = 0;
    __syncthreads();
    int e0 = blockIdx.x * EPB;
    int e1 = e0 + EPB; if (e1 > NE) e1 = NE;
    for (int e = e0 + threadIdx.x; e < e1; e += 256)
        atomicAdd(&lh[((unsigned)dst[e]) >> 8], 1);
    __syncthreads();
    for (int j = threadIdx.x; j < NBKT; j += 256)
        histM[j * NBLK + blockIdx.x] = lh[j];
}

// ---------- 2-level scan over SCN elements; scan3 folded into consumers ----------
__global__ void scan1_kernel(int* __restrict__ data, int* __restrict__ bsum, int n) {
    __shared__ int tmp[256];
    int tid = threadIdx.x, gid = blockIdx.x * 256 + tid;
    int v = (gid < n) ? data[gid] : 0;
    tmp[tid] = v;
    __syncthreads();
    for (int off = 1; off < 256; off <<= 1) {
        int t = (tid >= off) ? tmp[tid - off] : 0;
        __syncthreads();
        tmp[tid] += t;
        __syncthreads();
    }
    if (gid < n) data[gid] = tmp[tid] - v;   // block-local exclusive
    if (tid == 255) bsum[blockIdx.x] = tmp[255];
}

__global__ void scan2_kernel(int* __restrict__ bsum, int nb) {
    __shared__ int tmp[1024];
    int tid = threadIdx.x;
    int v = (tid < nb) ? bsum[tid] : 0;
    tmp[tid] = v;
    __syncthreads();
    for (int off = 1; off < 1024; off <<= 1) {
        int t = (tid >= off) ? tmp[tid - off] : 0;
        __syncthreads();
        tmp[tid] += t;
        __syncthreads();
    }
    if (tid < nb) bsum[tid] = tmp[tid] - v;
}

// ---------- phase 2: scatter edges into bucket-sorted ebuf ----------
__global__ void scatter2_kernel(const int* __restrict__ src, const int* __restrict__ dst,
                                const int* __restrict__ histM, const int* __restrict__ bsum,
                                unsigned* __restrict__ ebuf) {
    __shared__ int lc[NBKT];
    for (int j = threadIdx.x; j < NBKT; j += 256) {
        int idx = j * NBLK + blockIdx.x;
        lc[j] = histM[idx] + bsum[idx >> 8];
    }
    __syncthreads();
    int e0 = blockIdx.x * EPB;
    int e1 = e0 + EPB; if (e1 > NE) e1 = NE;
    for (int e = e0 + threadIdx.x; e < e1; e += 256) {
        int d = dst[e];
        int s = src[e];
        int pos = atomicAdd(&lc[((unsigned)d) >> 8], 1);
        ebuf[pos] = ((unsigned)s << 8) | (unsigned)(d & 255);
    }
}

// ---------- merged: per-bucket degree + dinv + rs (LDS scan) + CSR fill ----------
__global__ __launch_bounds__(256) void degcsr_kernel(
    const unsigned* __restrict__ ebuf, const int* __restrict__ histM,
    const int* __restrict__ bsum, int* __restrict__ rs, float* __restrict__ dinv,
    unsigned* __restrict__ csr) {
    __shared__ int cnt[BSZ];
    __shared__ int pfx[BSZ];
    int b = blockIdx.x;
    int i0 = b * NBLK;
    int s0 = histM[i0] + bsum[i0 >> 8];
    int s1 = NE;
    if (b + 1 < NBKT) {
        int i1 = (b + 1) * NBLK;
        s1 = histM[i1] + bsum[i1 >> 8];
    }
    cnt[threadIdx.x] = 0;
    __syncthreads();
    for (int i = s0 + threadIdx.x; i < s1; i += 256)
        atomicAdd(&cnt[ebuf[i] & 255], 1);
    __syncthreads();
    int v = cnt[threadIdx.x];
    pfx[threadIdx.x] = v;
    __syncthreads();
    for (int off = 1; off < 256; off <<= 1) {
        int t = (threadIdx.x >= off) ? pfx[threadIdx.x - off] : 0;
        __syncthreads();
        pfx[threadIdx.x] += t;
        __syncthreads();
    }
    int myrs = s0 + pfx[threadIdx.x] - v;   // exclusive
    int node = b * BSZ + threadIdx.x;
    if (node < NN) {
        rs[node] = myrs;
        dinv[node] = rsqrtf((float)v + 1.0f);
    }
    if (node == NN) rs[NN] = NE;
    __syncthreads();
    cnt[threadIdx.x] = 0;        // reuse as cursor
    pfx[threadIdx.x] = myrs;     // row base per local node
    __syncthreads();
    for (int i = s0 + threadIdx.x; i < s1; i += 256) {
        unsigned rec = ebuf[i];
        int nl = rec & 255;
        int pos = atomicAdd(&cnt[nl], 1);
        csr[pfx[nl] + pos] = rec >> 8;
    }
}

// ---------- merged weight conversion (both layers) ----------
__global__ void convw2_kernel(const float* __restrict__ W1, const float* __restrict__ W2,
                              unsigned short* __restrict__ Wt1, unsigned short* __restrict__ Wt2) {
    int idx = blockIdx.x * 256 + threadIdx.x;
    if (idx < C1 * KP1) {
        int c = idx / KP1, k = idx % KP1;
        Wt1[idx] = f2bf((k < INC) ? W1[k * C1 + c] : 0.f);
    } else {
        int j = idx - C1 * KP1;
        if (j < C2 * C1) {
            int c = j / C1, k = j % C1;
            Wt2[j] = f2bf(W2[k * C2 + c]);
        }
    }
}

// ---------- gemm1: hw1s = bf16(dinv[n] * (x @ W1)) ----------
__global__ __launch_bounds__(256) void gemm1_mfma(const float* __restrict__ x,
                                                  const unsigned short* __restrict__ Wt1,
                                                  const float* __restrict__ dinv,
                                                  unsigned short* __restrict__ hw1s) {
    int wave = threadIdx.x >> 6, lane = threadIdx.x & 63;
    int r = lane & 15, kg = lane >> 4;
    int row0 = blockIdx.x * 64 + wave * 16;
    const float* arow = x + (size_t)(row0 + r) * INC;
    bf16x8 a[3];
    #pragma unroll
    for (int t = 0; t < 3; ++t) {
        union { bf16x8 v; unsigned short u[8]; } tmp;
        #pragma unroll
        for (int j = 0; j < 8; ++j) {
            int k = t * 32 + kg * 8 + j;
            tmp.u[j] = (k < INC) ? f2bf(arow[k]) : (unsigned short)0;
        }
        a[t] = tmp.v;
    }
    float dsc[4];
    #pragma unroll
    for (int i = 0; i < 4; ++i) dsc[i] = dinv[row0 + kg * 4 + i];
    #pragma unroll
    for (int nt = 0; nt < 4; ++nt) {
        const unsigned short* wrow = Wt1 + (size_t)(nt * 16 + r) * KP1 + kg * 8;
        bf16x8 b0 = *(const bf16x8*)(wrow);
        bf16x8 b1 = *(const bf16x8*)(wrow + 32);
        bf16x8 b2 = *(const bf16x8*)(wrow + 64);
        f32x4 acc = {0.f, 0.f, 0.f, 0.f};
        acc = __builtin_amdgcn_mfma_f32_16x16x32_bf16(a[0], b0, acc, 0, 0, 0);
        acc = __builtin_amdgcn_mfma_f32_16x16x32_bf16(a[1], b1, acc, 0, 0, 0);
        acc = __builtin_amdgcn_mfma_f32_16x16x32_bf16(a[2], b2, acc, 0, 0, 0);
        unsigned short* cb = hw1s + (size_t)(row0 + kg * 4) * C1 + nt * 16 + r;
        #pragma unroll
        for (int i = 0; i < 4; ++i) cb[(size_t)i * C1] = f2bf(acc[i] * dsc[i]);
    }
}

// ---------- 8-lane-per-node CSR gather, 16B loads (8 ch per lane) ----------
// EP=1: out = bf16(relu(dinv*(acc+self) + bias) * dinv)
// EP=2: out = bf16(dinv*(acc+self))
template <int EP>
__global__ __launch_bounds__(256) void agg_csr_kernel(
    const unsigned* __restrict__ csr, const int* __restrict__ rs,
    const float* __restrict__ dinv, const unsigned short* __restrict__ vin,
    const float* __restrict__ bias, unsigned short* __restrict__ vout) {
    int node = blockIdx.x * 32 + (threadIdx.x >> 3);
    int l = threadIdx.x & 7;
    int c0 = l * 8;
    int start = rs[node], len = rs[node + 1] - start;
    float a0 = 0.f, a1 = 0.f, a2 = 0.f, a3 = 0.f;
    float a4 = 0.f, a5 = 0.f, a6 = 0.f, a7 = 0.f;
    int e = 0;
    for (; e + 2 <= len; e += 2) {
        unsigned sA = csr[start + e], sB = csr[start + e + 1];
        uint4 ra = *(const uint4*)(vin + (size_t)sA * 64 + c0);
        uint4 rb = *(const uint4*)(vin + (size_t)sB * 64 + c0);
        a0 += bflo(ra.x) + bflo(rb.x);
        a1 += bfhi(ra.x) + bfhi(rb.x);
        a2 += bflo(ra.y) + bflo(rb.y);
        a3 += bfhi(ra.y) + bfhi(rb.y);
        a4 += bflo(ra.z) + bflo(rb.z);
        a5 += bfhi(ra.z) + bfhi(rb.z);
        a6 += bflo(ra.w) + bflo(rb.w);
        a7 += bfhi(ra.w) + bfhi(rb.w);
    }
    if (e < len) {
        unsigned sA = csr[start + e];
        uint4 ra = *(const uint4*)(vin + (size_t)sA * 64 + c0);
        a0 += bflo(ra.x); a1 += bfhi(ra.x);
        a2 += bflo(ra.y); a3 += bfhi(ra.y);
        a4 += bflo(ra.z); a5 += bfhi(ra.z);
        a6 += bflo(ra.w); a7 += bfhi(ra.w);
    }
    uint4 sv = *(const uint4*)(vin + (size_t)node * 64 + c0);
    a0 += bflo(sv.x); a1 += bfhi(sv.x);
    a2 += bflo(sv.y); a3 += bfhi(sv.y);
    a4 += bflo(sv.z); a5 += bfhi(sv.z);
    a6 += bflo(sv.w); a7 += bfhi(sv.w);
    float d = dinv[node];
    a0 *= d; a1 *= d; a2 *= d; a3 *= d; a4 *= d; a5 *= d; a6 *= d; a7 *= d;
    if (EP == 1) {
        a0 = fmaxf(a0 + bias[c0 + 0], 0.f) * d;
        a1 = fmaxf(a1 + bias[c0 + 1], 0.f) * d;
        a2 = fmaxf(a2 + bias[c0 + 2], 0.f) * d;
        a3 = fmaxf(a3 + bias[c0 + 3], 0.f) * d;
        a4 = fmaxf(a4 + bias[c0 + 4], 0.f) * d;
        a5 = fmaxf(a5 + bias[c0 + 5], 0.f) * d;
        a6 = fmaxf(a6 + bias[c0 + 6], 0.f) * d;
        a7 = fmaxf(a7 + bias[c0 + 7], 0.f) * d;
    }
    uint4 o;
    o.x = (unsigned)f2bf(a0) | ((unsigned)f2bf(a1) << 16);
    o.y = (unsigned)f2bf(a2) | ((unsigned)f2bf(a3) << 16);
    o.z = (unsigned)f2bf(a4) | ((unsigned)f2bf(a5) << 16);
    o.w = (unsigned)f2bf(a6) | ((unsigned)f2bf(a7) << 16);
    *(uint4*)(vout + (size_t)node * 64 + c0) = o;
}

// ---------- gemm2: h2 = bf16(relu(aggH @ W2 + b2)) ----------
__global__ __launch_bounds__(256) void gemm2_mfma(const unsigned short* __restrict__ aggH,
                                                  const unsigned short* __restrict__ Wt2,
                                                  const float* __restrict__ b2,
                                                  unsigned short* __restrict__ h2) {
    int wave = threadIdx.x >> 6, lane = threadIdx.x & 63;
    int r = lane & 15, kg = lane >> 4;
    int row0 = blockIdx.x * 64 + wave * 16;
    const unsigned short* arow = aggH + (size_t)(row0 + r) * 64 + kg * 8;
    bf16x8 a0 = *(const bf16x8*)(arow);
    bf16x8 a1 = *(const bf16x8*)(arow + 32);
    #pragma unroll
    for (int nt = 0; nt < 8; ++nt) {
        const unsigned short* wrow = Wt2 + (size_t)(nt * 16 + r) * C1 + kg * 8;
        bf16x8 b0 = *(const bf16x8*)(wrow);
        bf16x8 b1 = *(const bf16x8*)(wrow + 32);
        f32x4 acc = {0.f, 0.f, 0.f, 0.f};
        acc = __builtin_amdgcn_mfma_f32_16x16x32_bf16(a0, b0, acc, 0, 0, 0);
        acc = __builtin_amdgcn_mfma_f32_16x16x32_bf16(a1, b1, acc, 0, 0, 0);
        int col = nt * 16 + r;
        float bb = b2[col];
        unsigned short* cb = h2 + (size_t)(row0 + kg * 4) * C2 + col;
        #pragma unroll
        for (int i = 0; i < 4; ++i) cb[(size_t)i * C2] = f2bf(fmaxf(acc[i] + bb, 0.f));
    }
}

// ---------- fused mean-pool + final FC ----------
__device__ __forceinline__ int lbound(const int* __restrict__ a, int n, int key) {
    int lo = 0, hi = n;
    while (lo < hi) {
        int mid = (lo + hi) >> 1;
        if (a[mid] < key) lo = mid + 1; else hi = mid;
    }
    return lo;
}

__global__ __launch_bounds__(256) void pool_fc_kernel(const unsigned short* __restrict__ h2,
                                                      const int* __restrict__ batch,
                                                      const float* __restrict__ fcw,
                                                      const float* __restrict__ fcb,
                                                      float* __restrict__ out) {
    __shared__ float ps[512];
    __shared__ float pr[128];
    int g = blockIdx.x;
    int lo = lbound(batch, NN, g);
    int hi = lbound(batch, NN, g + 1);
    int cnt = hi - lo;
    int rg = threadIdx.x >> 6;
    int p = threadIdx.x & 63;
    float s0 = 0.f, s1 = 0.f;
    for (int r = lo + rg; r < hi; r += 4) {
        unsigned v = *(const unsigned*)(h2 + (size_t)r * C2 + p * 2);
        s0 += bflo(v);
        s1 += bfhi(v);
    }
    ps[threadIdx.x * 2 + 0] = s0;
    ps[threadIdx.x * 2 + 1] = s1;
    __syncthreads();
    if (threadIdx.x < 64) {
        float inv = 1.0f / (float)((cnt > 0) ? cnt : 1);
        int t = threadIdx.x;
        float r0 = 0.f, r1 = 0.f;
        #pragma unroll
        for (int k = 0; k < 4; ++k) {
            r0 += ps[(k * 64 + t) * 2 + 0];
            r1 += ps[(k * 64 + t) * 2 + 1];
        }
        pr[2 * t + 0] = r0 * inv;
        pr[2 * t + 1] = r1 * inv;
    }
    __syncthreads();
    if (threadIdx.x < 128) {
        int o = threadIdx.x;
        float acc = fcb[o];
        #pragma unroll 8
        for (int k = 0; k < C2; ++k) acc += pr[k] * fcw[k * ODIM + o];
        out[(size_t)g * ODIM + o] = acc;
    }
}

extern "C" void kernel_launch(void* const* d_in, const int* in_sizes, int n_in,
                              void* d_out, int out_size, void* d_ws, size_t ws_size,
                              hipStream_t stream) {
    const float* x   = (const float*)d_in[0];
    const int*   ei  = (const int*)d_in[1];
    const int*   bat = (const int*)d_in[2];
    const float* W1  = (const float*)d_in[3];
    const float* b1  = (const float*)d_in[4];
    const float* W2  = (const float*)d_in[5];
    const float* b2  = (const float*)d_in[6];
    const float* fcw = (const float*)d_in[7];
    const float* fcb = (const float*)d_in[8];
    float* out = (float*)d_out;

    const int* src = ei;        // edge_index[0]
    const int* dst = ei + NE;   // edge_index[1]

    char* ws = (char*)d_ws;
    int* histM   = (int*)ws;            ws += alignup((size_t)SCN * 4);
    int* bsum    = (int*)ws;            ws += alignup(1024 * 4);
    int* rs      = (int*)ws;            ws += alignup((size_t)(NN + 1) * 4);
    float* dinv  = (float*)ws;          ws += alignup((size_t)NN * 4);
    unsigned short* Wt1 = (unsigned short*)ws;  ws += alignup((size_t)C1 * KP1 * 2);
    unsigned short* Wt2 = (unsigned short*)ws;  ws += alignup((size_t)C2 * C1 * 2);
    unsigned short* hw1s = (unsigned short*)ws; ws += alignup((size_t)NN * C1 * 2);
    unsigned short* aggH = hw1s;        // reuse: hw1s dead after agg_csr<1>
    // h2 (51.2MB) aliases [ebuf | csr | h1s] -- all dead before gemm2
    unsigned* ebuf = (unsigned*)ws;     ws += alignup((size_t)NE * 4);
    unsigned* csr  = (unsigned*)ws;     ws += alignup((size_t)NE * 4);
    unsigned short* h1s = (unsigned short*)ws;  ws += alignup((size_t)NN * C1 * 2);
    unsigned short* h2 = (unsigned short*)ebuf;

    // ---- edge binning (bucket = dst>>8) ----
    hist1_kernel<<<NBLK, 256, 0, stream>>>(dst, histM);
    const int SCB = (SCN + 255) / 256;  // 599
    scan1_kernel<<<SCB, 256, 0, stream>>>(histM, bsum, SCN);
    scan2_kernel<<<1, 1024, 0, stream>>>(bsum, SCB);
    scatter2_kernel<<<NBLK, 256, 0, stream>>>(src, dst, histM, bsum, ebuf);

    // ---- degrees + dinv + rs + CSR (single merged kernel) ----
    degcsr_kernel<<<NBKT, 256, 0, stream>>>(ebuf, histM, bsum, rs, dinv, csr);

    // ---- weights ----
    convw2_kernel<<<(C1 * KP1 + C2 * C1 + 255) / 256, 256, 0, stream>>>(W1, W2, Wt1, Wt2);

    // ---- layer 1: GEMM (pre-scaled rows) then gather ----
    gemm1_mfma<<<NN / 64, 256, 0, stream>>>(x, Wt1, dinv, hw1s);
    agg_csr_kernel<1><<<NN / 32, 256, 0, stream>>>(csr, rs, dinv, hw1s, b1, h1s);

    // ---- layer 2: aggregate first (linearity), then GEMM + relu -> h2 ----
    agg_csr_kernel<2><<<NN / 32, 256, 0, stream>>>(csr, rs, dinv, h1s, b1, aggH);
    gemm2_mfma<<<NN / 64, 256, 0, stream>>>(aggH, Wt2, b2, h2);

    // ---- fused mean-pool + FC ----
    pool_fc_kernel<<<NG, 256, 0, stream>>>(h2, bat, fcw, fcb, out);
}

// Round 9
// 299.653 us; speedup vs baseline: 10.2984x; 1.0160x over previous
//
#include <hip/hip_runtime.h>
#include <hip/hip_bf16.h>

#define NN 200000
#define NE 3200000
#define NG 4096
#define INC 78
#define C1 64
#define C2 128
#define ODIM 128
#define KP1 96      // layer-1 K padded to 3x32

#define BSZ 256     // nodes per bucket
#define NBKT 782    // ceil(NN/BSZ)
#define NBLK 196    // binning blocks
#define EPB 16327   // ceil(NE/NBLK)
#define SCN (NBKT*NBLK)
#define MAXREC 12288  // bucket staging cap: mean 4096, std 64 -> 128 sigma margin

using bf16 = __hip_bfloat16;
typedef __attribute__((ext_vector_type(8))) short bf16x8;
typedef __attribute__((ext_vector_type(4))) float f32x4;

static inline size_t alignup(size_t x) { return (x + 255) & ~size_t(255); }

__device__ __forceinline__ float bflo(unsigned u) { return __uint_as_float(u << 16); }
__device__ __forceinline__ float bfhi(unsigned u) { return __uint_as_float(u & 0xffff0000u); }
__device__ __forceinline__ unsigned short f2bf(float f) {
    __hip_bfloat16 h = __float2bfloat16(f);
    return *reinterpret_cast<unsigned short*>(&h);
}

// ---------- phase 1: per-(bucket,block) histogram of dst>>8 ----------
__global__ void hist1_kernel(const int* __restrict__ dst, int* __restrict__ histM) {
    __shared__ int lh[NBKT];
    for (int j = threadIdx.x; j < NBKT; j += 256) lh[j] = 0;
    __syncthreads();
    int e0 = blockIdx.x * EPB;
    int e1 = e0 + EPB; if (e1 > NE) e1 = NE;
    for (int e = e0 + threadIdx.x; e < e1; e += 256)
        atomicAdd(&lh[((unsigned)dst[e]) >> 8], 1);
    __syncthreads();
    for (int j = threadIdx.x; j < NBKT; j += 256)
        histM[j * NBLK + blockIdx.x] = lh[j];
}

// ---------- 2-level scan over SCN elements ----------
__global__ void scan1_kernel(int* __restrict__ data, int* __restrict__ bsum, int n) {
    __shared__ int tmp[256];
    int tid = threadIdx.x, gid = blockIdx.x * 256 + tid;
    int v = (gid < n) ? data[gid] : 0;
    tmp[tid] = v;
    __syncthreads();
    for (int off = 1; off < 256; off <<= 1) {
        int t = (tid >= off) ? tmp[tid - off] : 0;
        __syncthreads();
        tmp[tid] += t;
        __syncthreads();
    }
    if (gid < n) data[gid] = tmp[tid] - v;   // block-local exclusive
    if (tid == 255) bsum[blockIdx.x] = tmp[255];
}

__global__ void scan2_kernel(int* __restrict__ bsum, int nb) {
    __shared__ int tmp[1024];
    int tid = threadIdx.x;
    int v = (tid < nb) ? bsum[tid] : 0;
    tmp[tid] = v;
    __syncthreads();
    for (int off = 1; off < 1024; off <<= 1) {
        int t = (tid >= off) ? tmp[tid - off] : 0;
        __syncthreads();
        tmp[tid] += t;
        __syncthreads();
    }
    if (tid < nb) bsum[tid] = tmp[tid] - v;
}

// ---------- phase 2: scatter edges into bucket-sorted ecsr ----------
__global__ void scatter2_kernel(const int* __restrict__ src, const int* __restrict__ dst,
                                const int* __restrict__ histM, const int* __restrict__ bsum,
                                unsigned* __restrict__ ecsr) {
    __shared__ int lc[NBKT];
    for (int j = threadIdx.x; j < NBKT; j += 256) {
        int idx = j * NBLK + blockIdx.x;
        lc[j] = histM[idx] + bsum[idx >> 8];
    }
    __syncthreads();
    int e0 = blockIdx.x * EPB;
    int e1 = e0 + EPB; if (e1 > NE) e1 = NE;
    for (int e = e0 + threadIdx.x; e < e1; e += 256) {
        int d = dst[e];
        int s = src[e];
        int pos = atomicAdd(&lc[((unsigned)d) >> 8], 1);
        ecsr[pos] = ((unsigned)s << 8) | (unsigned)(d & 255);
    }
}

// ---------- merged: stage bucket in LDS, degrees+dinv+rs, permute ecsr->CSR in place ----------
__global__ __launch_bounds__(256) void degcsr_kernel(
    const int* __restrict__ histM, const int* __restrict__ bsum,
    int* __restrict__ rs, float* __restrict__ dinv, unsigned* __restrict__ ecsr) {
    __shared__ int cnt[BSZ];
    __shared__ int pfx[BSZ];
    __shared__ unsigned recs[MAXREC];
    int b = blockIdx.x;
    int i0 = b * NBLK;
    int s0 = histM[i0] + bsum[i0 >> 8];
    int s1 = NE;
    if (b + 1 < NBKT) {
        int i1 = (b + 1) * NBLK;
        s1 = histM[i1] + bsum[i1 >> 8];
    }
    int nrec = s1 - s0;
    if (nrec > MAXREC) nrec = MAXREC;  // statistically impossible (128 sigma)
    cnt[threadIdx.x] = 0;
    for (int i = threadIdx.x; i < nrec; i += 256) recs[i] = ecsr[s0 + i];
    __syncthreads();
    for (int i = threadIdx.x; i < nrec; i += 256)
        atomicAdd(&cnt[recs[i] & 255], 1);
    __syncthreads();
    int v = cnt[threadIdx.x];
    pfx[threadIdx.x] = v;
    __syncthreads();
    for (int off = 1; off < 256; off <<= 1) {
        int t = (threadIdx.x >= off) ? pfx[threadIdx.x - off] : 0;
        __syncthreads();
        pfx[threadIdx.x] += t;
        __syncthreads();
    }
    int myrs = s0 + pfx[threadIdx.x] - v;   // exclusive
    int node = b * BSZ + threadIdx.x;
    if (node < NN) {
        rs[node] = myrs;
        dinv[node] = rsqrtf((float)v + 1.0f);
    }
    if (node == NN) rs[NN] = NE;
    __syncthreads();
    cnt[threadIdx.x] = 0;        // reuse as cursor
    pfx[threadIdx.x] = myrs;     // row base per local node
    __syncthreads();
    for (int i = threadIdx.x; i < nrec; i += 256) {
        unsigned rec = recs[i];
        int nl = rec & 255;
        int pos = atomicAdd(&cnt[nl], 1);
        ecsr[pfx[nl] + pos] = rec >> 8;   // in place: source staged in LDS
    }
}

// ---------- merged weight conversion (both layers) ----------
__global__ void convw2_kernel(const float* __restrict__ W1, const float* __restrict__ W2,
                              unsigned short* __restrict__ Wt1, unsigned short* __restrict__ Wt2) {
    int idx = blockIdx.x * 256 + threadIdx.x;
    if (idx < C1 * KP1) {
        int c = idx / KP1, k = idx % KP1;
        Wt1[idx] = f2bf((k < INC) ? W1[k * C1 + c] : 0.f);
    } else {
        int j = idx - C1 * KP1;
        if (j < C2 * C1) {
            int c = j / C1, k = j % C1;
            Wt2[j] = f2bf(W2[k * C2 + c]);
        }
    }
}

// ---------- gemm1: hw1s = bf16(dinv[n] * (x @ W1)); x staged via coalesced float4 ----------
__global__ __launch_bounds__(256) void gemm1_mfma(const float* __restrict__ x,
                                                  const unsigned short* __restrict__ Wt1,
                                                  const float* __restrict__ dinv,
                                                  unsigned short* __restrict__ hw1s) {
    __shared__ float xs[64 * INC];   // 19968 B
    const float4* gsrc = (const float4*)(x + (size_t)blockIdx.x * 64 * INC);
    float4* ldst = (float4*)xs;
    #pragma unroll
    for (int t = 0; t < 5; ++t) {
        int i = t * 256 + threadIdx.x;
        if (i < (64 * INC) / 4) ldst[i] = gsrc[i];
    }
    __syncthreads();
    int wave = threadIdx.x >> 6, lane = threadIdx.x & 63;
    int r = lane & 15, kg = lane >> 4;
    int lrow = wave * 16 + r;
    int row0 = blockIdx.x * 64 + wave * 16;
    const float* arow = xs + lrow * INC;
    bf16x8 a[3];
    #pragma unroll
    for (int t = 0; t < 3; ++t) {
        union { bf16x8 v; unsigned short u[8]; } tmp;
        #pragma unroll
        for (int j = 0; j < 8; ++j) {
            int k = t * 32 + kg * 8 + j;
            tmp.u[j] = (k < INC) ? f2bf(arow[k]) : (unsigned short)0;
        }
        a[t] = tmp.v;
    }
    float dsc[4];
    #pragma unroll
    for (int i = 0; i < 4; ++i) dsc[i] = dinv[row0 + kg * 4 + i];
    #pragma unroll
    for (int nt = 0; nt < 4; ++nt) {
        const unsigned short* wrow = Wt1 + (size_t)(nt * 16 + r) * KP1 + kg * 8;
        bf16x8 b0 = *(const bf16x8*)(wrow);
        bf16x8 b1 = *(const bf16x8*)(wrow + 32);
        bf16x8 b2 = *(const bf16x8*)(wrow + 64);
        f32x4 acc = {0.f, 0.f, 0.f, 0.f};
        acc = __builtin_amdgcn_mfma_f32_16x16x32_bf16(a[0], b0, acc, 0, 0, 0);
        acc = __builtin_amdgcn_mfma_f32_16x16x32_bf16(a[1], b1, acc, 0, 0, 0);
        acc = __builtin_amdgcn_mfma_f32_16x16x32_bf16(a[2], b2, acc, 0, 0, 0);
        unsigned short* cb = hw1s + (size_t)(row0 + kg * 4) * C1 + nt * 16 + r;
        #pragma unroll
        for (int i = 0; i < 4; ++i) cb[(size_t)i * C1] = f2bf(acc[i] * dsc[i]);
    }
}

// ---------- gather core: 8-lane group, 16B row fragments, unroll 4 ----------
__device__ __forceinline__ void gather_node(
    const unsigned* __restrict__ csr, int start, int len,
    const unsigned short* __restrict__ vin, int c0,
    float& a0, float& a1, float& a2, float& a3,
    float& a4, float& a5, float& a6, float& a7) {
    int e = 0;
    for (; e + 4 <= len; e += 4) {
        unsigned s0 = csr[start + e + 0];
        unsigned s1 = csr[start + e + 1];
        unsigned s2 = csr[start + e + 2];
        unsigned s3 = csr[start + e + 3];
        uint4 r0 = *(const uint4*)(vin + (size_t)s0 * 64 + c0);
        uint4 r1 = *(const uint4*)(vin + (size_t)s1 * 64 + c0);
        uint4 r2 = *(const uint4*)(vin + (size_t)s2 * 64 + c0);
        uint4 r3 = *(const uint4*)(vin + (size_t)s3 * 64 + c0);
        a0 += (bflo(r0.x) + bflo(r1.x)) + (bflo(r2.x) + bflo(r3.x));
        a1 += (bfhi(r0.x) + bfhi(r1.x)) + (bfhi(r2.x) + bfhi(r3.x));
        a2 += (bflo(r0.y) + bflo(r1.y)) + (bflo(r2.y) + bflo(r3.y));
        a3 += (bfhi(r0.y) + bfhi(r1.y)) + (bfhi(r2.y) + bfhi(r3.y));
        a4 += (bflo(r0.z) + bflo(r1.z)) + (bflo(r2.z) + bflo(r3.z));
        a5 += (bfhi(r0.z) + bfhi(r1.z)) + (bfhi(r2.z) + bfhi(r3.z));
        a6 += (bflo(r0.w) + bflo(r1.w)) + (bflo(r2.w) + bflo(r3.w));
        a7 += (bfhi(r0.w) + bfhi(r1.w)) + (bfhi(r2.w) + bfhi(r3.w));
    }
    for (; e < len; ++e) {
        unsigned s = csr[start + e];
        uint4 ra = *(const uint4*)(vin + (size_t)s * 64 + c0);
        a0 += bflo(ra.x); a1 += bfhi(ra.x);
        a2 += bflo(ra.y); a3 += bfhi(ra.y);
        a4 += bflo(ra.z); a5 += bfhi(ra.z);
        a6 += bflo(ra.w); a7 += bfhi(ra.w);
    }
}

// ---------- layer-1 aggregate: h1s = bf16(relu(dinv*(acc+self) + b1) * dinv) ----------
__global__ __launch_bounds__(256) void agg1_kernel(
    const unsigned* __restrict__ csr, const int* __restrict__ rs,
    const float* __restrict__ dinv, const unsigned short* __restrict__ vin,
    const float* __restrict__ bias, unsigned short* __restrict__ vout) {
    int node = blockIdx.x * 32 + (threadIdx.x >> 3);
    int l = threadIdx.x & 7;
    int c0 = l * 8;
    int start = rs[node], len = rs[node + 1] - start;
    float a0 = 0.f, a1 = 0.f, a2 = 0.f, a3 = 0.f, a4 = 0.f, a5 = 0.f, a6 = 0.f, a7 = 0.f;
    gather_node(csr, start, len, vin, c0, a0, a1, a2, a3, a4, a5, a6, a7);
    uint4 sv = *(const uint4*)(vin + (size_t)node * 64 + c0);
    a0 += bflo(sv.x); a1 += bfhi(sv.x);
    a2 += bflo(sv.y); a3 += bfhi(sv.y);
    a4 += bflo(sv.z); a5 += bfhi(sv.z);
    a6 += bflo(sv.w); a7 += bfhi(sv.w);
    float d = dinv[node];
    a0 = fmaxf(a0 * d + bias[c0 + 0], 0.f) * d;
    a1 = fmaxf(a1 * d + bias[c0 + 1], 0.f) * d;
    a2 = fmaxf(a2 * d + bias[c0 + 2], 0.f) * d;
    a3 = fmaxf(a3 * d + bias[c0 + 3], 0.f) * d;
    a4 = fmaxf(a4 * d + bias[c0 + 4], 0.f) * d;
    a5 = fmaxf(a5 * d + bias[c0 + 5], 0.f) * d;
    a6 = fmaxf(a6 * d + bias[c0 + 6], 0.f) * d;
    a7 = fmaxf(a7 * d + bias[c0 + 7], 0.f) * d;
    uint4 o;
    o.x = (unsigned)f2bf(a0) | ((unsigned)f2bf(a1) << 16);
    o.y = (unsigned)f2bf(a2) | ((unsigned)f2bf(a3) << 16);
    o.z = (unsigned)f2bf(a4) | ((unsigned)f2bf(a5) << 16);
    o.w = (unsigned)f2bf(a6) | ((unsigned)f2bf(a7) << 16);
    *(uint4*)(vout + (size_t)node * 64 + c0) = o;
}

// ---------- fused layer-2: gather 64 nodes -> LDS A -> MFMA W2 -> relu -> h2 ----------
__global__ __launch_bounds__(256) void agg2g_mfma(
    const unsigned* __restrict__ csr, const int* __restrict__ rs,
    const float* __restrict__ dinv, const unsigned short* __restrict__ h1s,
    const unsigned short* __restrict__ Wt2, const float* __restrict__ b2,
    unsigned short* __restrict__ h2) {
    __shared__ unsigned short A[64 * 72];   // stride 72 -> 2-way-max bank conflicts
    int grp = threadIdx.x >> 3;
    int l = threadIdx.x & 7;
    int c0 = l * 8;
    #pragma unroll
    for (int half = 0; half < 2; ++half) {
        int nl = grp + half * 32;
        int node = blockIdx.x * 64 + nl;
        int start = rs[node], len = rs[node + 1] - start;
        float a0 = 0.f, a1 = 0.f, a2 = 0.f, a3 = 0.f, a4 = 0.f, a5 = 0.f, a6 = 0.f, a7 = 0.f;
        gather_node(csr, start, len, h1s, c0, a0, a1, a2, a3, a4, a5, a6, a7);
        uint4 sv = *(const uint4*)(h1s + (size_t)node * 64 + c0);
        a0 += bflo(sv.x); a1 += bfhi(sv.x);
        a2 += bflo(sv.y); a3 += bfhi(sv.y);
        a4 += bflo(sv.z); a5 += bfhi(sv.z);
        a6 += bflo(sv.w); a7 += bfhi(sv.w);
        float d = dinv[node];
        uint4 o;
        o.x = (unsigned)f2bf(a0 * d) | ((unsigned)f2bf(a1 * d) << 16);
        o.y = (unsigned)f2bf(a2 * d) | ((unsigned)f2bf(a3 * d) << 16);
        o.z = (unsigned)f2bf(a4 * d) | ((unsigned)f2bf(a5 * d) << 16);
        o.w = (unsigned)f2bf(a6 * d) | ((unsigned)f2bf(a7 * d) << 16);
        *(uint4*)(A + nl * 72 + c0) = o;
    }
    __syncthreads();
    int wave = threadIdx.x >> 6, lane = threadIdx.x & 63;
    int r = lane & 15, kg = lane >> 4;
    int lrow = wave * 16 + r;
    int row0 = blockIdx.x * 64 + wave * 16;
    bf16x8 a0 = *(const bf16x8*)(A + lrow * 72 + kg * 8);
    bf16x8 a1 = *(const bf16x8*)(A + lrow * 72 + 32 + kg * 8);
    #pragma unroll
    for (int nt = 0; nt < 8; ++nt) {
        const unsigned short* wrow = Wt2 + (size_t)(nt * 16 + r) * C1 + kg * 8;
        bf16x8 b0 = *(const bf16x8*)(wrow);
        bf16x8 b1 = *(const bf16x8*)(wrow + 32);
        f32x4 acc = {0.f, 0.f, 0.f, 0.f};
        acc = __builtin_amdgcn_mfma_f32_16x16x32_bf16(a0, b0, acc, 0, 0, 0);
        acc = __builtin_amdgcn_mfma_f32_16x16x32_bf16(a1, b1, acc, 0, 0, 0);
        int col = nt * 16 + r;
        float bb = b2[col];
        unsigned short* cb = h2 + (size_t)(row0 + kg * 4) * C2 + col;
        #pragma unroll
        for (int i = 0; i < 4; ++i) cb[(size_t)i * C2] = f2bf(fmaxf(acc[i] + bb, 0.f));
    }
}

// ---------- fused mean-pool + final FC ----------
__device__ __forceinline__ int lbound(const int* __restrict__ a, int n, int key) {
    int lo = 0, hi = n;
    while (lo < hi) {
        int mid = (lo + hi) >> 1;
        if (a[mid] < key) lo = mid + 1; else hi = mid;
    }
    return lo;
}

__global__ __launch_bounds__(256) void pool_fc_kernel(const unsigned short* __restrict__ h2,
                                                      const int* __restrict__ batch,
                                                      const float* __restrict__ fcw,
                                                      const float* __restrict__ fcb,
                                                      float* __restrict__ out) {
    __shared__ float ps[512];
    __shared__ float pr[128];
    int g = blockIdx.x;
    int lo = lbound(batch, NN, g);
    int hi = lbound(batch, NN, g + 1);
    int cnt = hi - lo;
    int rg = threadIdx.x >> 6;
    int p = threadIdx.x & 63;
    float s0 = 0.f, s1 = 0.f;
    for (int r = lo + rg; r < hi; r += 4) {
        unsigned v = *(const unsigned*)(h2 + (size_t)r * C2 + p * 2);
        s0 += bflo(v);
        s1 += bfhi(v);
    }
    ps[threadIdx.x * 2 + 0] = s0;
    ps[threadIdx.x * 2 + 1] = s1;
    __syncthreads();
    if (threadIdx.x < 64) {
        float inv = 1.0f / (float)((cnt > 0) ? cnt : 1);
        int t = threadIdx.x;
        float r0 = 0.f, r1 = 0.f;
        #pragma unroll
        for (int k = 0; k < 4; ++k) {
            r0 += ps[(k * 64 + t) * 2 + 0];
            r1 += ps[(k * 64 + t) * 2 + 1];
        }
        pr[2 * t + 0] = r0 * inv;
        pr[2 * t + 1] = r1 * inv;
    }
    __syncthreads();
    if (threadIdx.x < 128) {
        int o = threadIdx.x;
        float acc = fcb[o];
        #pragma unroll 8
        for (int k = 0; k < C2; ++k) acc += pr[k] * fcw[k * ODIM + o];
        out[(size_t)g * ODIM + o] = acc;
    }
}

extern "C" void kernel_launch(void* const* d_in, const int* in_sizes, int n_in,
                              void* d_out, int out_size, void* d_ws, size_t ws_size,
                              hipStream_t stream) {
    const float* x   = (const float*)d_in[0];
    const int*   ei  = (const int*)d_in[1];
    const int*   bat = (const int*)d_in[2];
    const float* W1  = (const float*)d_in[3];
    const float* b1  = (const float*)d_in[4];
    const float* W2  = (const float*)d_in[5];
    const float* b2  = (const float*)d_in[6];
    const float* fcw = (const float*)d_in[7];
    const float* fcb = (const float*)d_in[8];
    float* out = (float*)d_out;

    const int* src = ei;        // edge_index[0]
    const int* dst = ei + NE;   // edge_index[1]

    char* ws = (char*)d_ws;
    int* histM   = (int*)ws;            ws += alignup((size_t)SCN * 4);
    int* bsum    = (int*)ws;            ws += alignup(1024 * 4);
    int* rs      = (int*)ws;            ws += alignup((size_t)(NN + 1) * 4);
    float* dinv  = (float*)ws;          ws += alignup((size_t)NN * 4);
    unsigned short* Wt1 = (unsigned short*)ws;  ws += alignup((size_t)C1 * KP1 * 2);
    unsigned short* Wt2 = (unsigned short*)ws;  ws += alignup((size_t)C2 * C1 * 2);
    unsigned short* hw1s = (unsigned short*)ws; ws += alignup((size_t)NN * C1 * 2);
    unsigned* ecsr = (unsigned*)ws;     ws += alignup((size_t)NE * 4);   // ebuf -> in-place CSR
    unsigned short* h1s = (unsigned short*)ws;  ws += alignup((size_t)NN * C1 * 2);
    unsigned short* h2 = (unsigned short*)ws;   ws += alignup((size_t)NN * C2 * 2);
    // total ~117.4 MB < proven-available ~118.1 MB

    // ---- edge binning (bucket = dst>>8) ----
    hist1_kernel<<<NBLK, 256, 0, stream>>>(dst, histM);
    const int SCB = (SCN + 255) / 256;  // 599
    scan1_kernel<<<SCB, 256, 0, stream>>>(histM, bsum, SCN);
    scan2_kernel<<<1, 1024, 0, stream>>>(bsum, SCB);
    scatter2_kernel<<<NBLK, 256, 0, stream>>>(src, dst, histM, bsum, ecsr);

    // ---- degrees + dinv + rs + in-place CSR ----
    degcsr_kernel<<<NBKT, 256, 0, stream>>>(histM, bsum, rs, dinv, ecsr);

    // ---- weights ----
    convw2_kernel<<<(C1 * KP1 + C2 * C1 + 255) / 256, 256, 0, stream>>>(W1, W2, Wt1, Wt2);

    // ---- layer 1: staged MFMA GEMM (pre-scaled rows) then gather ----
    gemm1_mfma<<<NN / 64, 256, 0, stream>>>(x, Wt1, dinv, hw1s);
    agg1_kernel<<<NN / 32, 256, 0, stream>>>(ecsr, rs, dinv, hw1s, b1, h1s);

    // ---- layer 2: fused gather + GEMM + relu -> h2 ----
    agg2g_mfma<<<NN / 64, 256, 0, stream>>>(ecsr, rs, dinv, h1s, Wt2, b2, h2);

    // ---- fused mean-pool + FC ----
    pool_fc_kernel<<<NG, 256, 0, stream>>>(h2, bat, fcw, fcb, out);
}